// Round 18
// baseline (259.648 us; speedup 1.0000x reference)
//
#include <hip/hip_runtime.h>
#include <hip/hip_fp16.h>
#include <math.h>

#define NN     40000
#define NT0    20000
#define NE     640000
#define NHOPS  8
#define RCAP   64
#define NRANGE 250                            // node ranges (160 nodes each)
#define SUBN   160                            // NRANGE * SUBN == NN exactly
#define SBCAP  512                            // per (xcd,range) bucket cap (avg 320)
#define GSTRIDE ((size_t)(NN + 1) * 128)      // elems per g buffer (row NN = dummy zero)

typedef _Float16 f16x8 __attribute__((ext_vector_type(8)));
typedef float    f32x4 __attribute__((ext_vector_type(4)));

// ---------------- setup: 3x weight transpose (f32 -> fp16 WT) + g dummy-row zero --
__global__ __launch_bounds__(256) void setup_kernel(
    const float* __restrict__ W0, _Float16* __restrict__ WT0,
    const float* __restrict__ W1, _Float16* __restrict__ WT1,
    const float* __restrict__ Wp, _Float16* __restrict__ WpT,
    unsigned* __restrict__ gbase)
{
    __shared__ float t[32][33];
    int b = blockIdx.x;
    const float* W; _Float16* WT; int K, lb;
    if (b < 32)      { W = W0; WT = WT0; K = 256; lb = b; }
    else if (b < 48) { W = W1; WT = WT1; K = 128; lb = b - 32; }
    else if (b < 64) { W = Wp; WT = WpT; K = 128; lb = b - 48; }
    else {
        int tt = (b - 64) * 256 + threadIdx.x;
        if (tt < 9 * 64) {
            int k = tt >> 6, j = tt & 63;
            gbase[(size_t)k * (GSTRIDE / 2) + ((size_t)NN << 6) + j] = 0u;
        }
        return;
    }
    int bk = (lb >> 2) * 32, bn = (lb & 3) * 32;
    int tx = threadIdx.x & 31, ty4 = (threadIdx.x >> 5) * 4;
#pragma unroll
    for (int i = 0; i < 4; ++i)
        t[ty4 + i][tx] = W[(size_t)(bk + ty4 + i) * 128 + bn + tx];
    __syncthreads();
#pragma unroll
    for (int i = 0; i < 4; ++i)
        WT[(size_t)(bn + ty4 + i) * K + bk + tx] = (_Float16)t[tx][ty4 + i];
}

// ---------------- phase A: partition edges into 8x250 XCD-private buckets --------
// 4 edges per thread; grid = NE/1024 = 625 blocks
__global__ __launch_bounds__(256) void partition_kernel(
    const int* __restrict__ src, const int* __restrict__ dst,
    unsigned* __restrict__ odeg8, unsigned* __restrict__ bptr,
    unsigned* __restrict__ ebuf)
{
    __shared__ unsigned lhist[NRANGE];
    __shared__ unsigned gbase[NRANGE];
    int tid = threadIdx.x;
    for (int i = tid; i < NRANGE; i += 256) lhist[i] = 0u;
    __syncthreads();
    int xcd = blockIdx.x & 7;
    unsigned* myodeg = odeg8 + xcd * NN;
    int e0 = blockIdx.x * 1024 + tid;
    int s[4], d[4], bb[4];
    unsigned r[4];
#pragma unroll
    for (int j = 0; j < 4; ++j) {
        int e = e0 + j * 256;
        s[j] = src[e]; d[j] = dst[e];
    }
#pragma unroll
    for (int j = 0; j < 4; ++j) {
        atomicAdd(&myodeg[s[j]], 1u);
        bb[j] = d[j] / SUBN;
        r[j] = atomicAdd(&lhist[bb[j]], 1u);
    }
    __syncthreads();
    for (int i = tid; i < NRANGE; i += 256)
        gbase[i] = atomicAdd(&bptr[xcd * NRANGE + i], lhist[i]);
    __syncthreads();
#pragma unroll
    for (int j = 0; j < 4; ++j) {
        unsigned p = gbase[bb[j]] + r[j];
        if (p < SBCAP)
            ebuf[(xcd * NRANGE + bb[j]) * SBCAP + p] = ((unsigned)s[j] << 16) | (unsigned)d[j];
    }
}

// ---------------- phase B: block b owns 160 nodes; scatter + fused norms ----------
__global__ __launch_bounds__(256) void scatter_kernel(
    const unsigned* __restrict__ ebuf, const unsigned* __restrict__ bptr,
    const unsigned* __restrict__ odeg8,
    unsigned* __restrict__ cnt, unsigned short* __restrict__ csr,
    float* __restrict__ ns, float* __restrict__ nsd, float* __restrict__ rns)
{
    __shared__ unsigned short csrL[SUBN * RCAP];   // 20,480 B
    __shared__ unsigned cntL[SUBN];
    int b = blockIdx.x;
    int lo = b * SUBN;
    int tid = threadIdx.x;
    const unsigned pat = (40000u << 16) | 40000u;
    for (int i = tid; i < SUBN * RCAP / 2; i += 256) ((unsigned*)csrL)[i] = pat;
    for (int i = tid; i < SUBN; i += 256) cntL[i] = 0u;
    __syncthreads();
#pragma unroll
    for (int x = 0; x < 8; ++x) {
        unsigned count = bptr[x * NRANGE + b];
        if (count > SBCAP) count = SBCAP;
        const unsigned* eb = ebuf + (size_t)(x * NRANGE + b) * SBCAP;
        for (unsigned i = tid; i < count; i += 256) {
            unsigned pk = eb[i];
            int d = (int)(pk & 0xFFFFu) - lo;
            unsigned p = atomicAdd(&cntL[d], 1u);
            if (p < RCAP) csrL[(d << 6) + (int)p] = (unsigned short)(pk >> 16);
        }
    }
    __syncthreads();
    int4* dst4 = (int4*)(csr + ((size_t)lo << 6));
    const int4* src4 = (const int4*)csrL;
    for (int i = tid; i < SUBN * 8; i += 256) dst4[i] = src4[i];
    for (int i = tid; i < SUBN; i += 256) {
        int node = lo + i;
        cnt[node] = cntL[i];
        unsigned odu = 0;
#pragma unroll
        for (int k = 0; k < 8; ++k) odu += odeg8[k * NN + node];
        float od = fmaxf((float)odu, 1.0f);
        float s = rsqrtf(od);
        float d = rsqrtf(fmaxf((float)cntL[i], 1.0f));
        ns[node] = s; nsd[node] = s * d; rns[node] = sqrtf(od);
    }
}

// ---------------- MFMA projection: g0[row0+r] = fp16((feat @ W + b) * ns) --------
template<int K>
__global__ __launch_bounds__(256) void projmm_kernel(
    const float* __restrict__ feat, const _Float16* __restrict__ WT,
    const float* __restrict__ b, const float* __restrict__ ns,
    __half* __restrict__ g0, int row0, int M)
{
    constexpr int LDB = K + 8;
    __shared__ _Float16 BT[128 * LDB];
    int tid = threadIdx.x;
    for (int idx = tid * 8; idx < 128 * K; idx += 256 * 8) {
        int n = idx / K, k = idx % K;
        *(f16x8*)(&BT[n * LDB + k]) = *(const f16x8*)(&WT[n * K + k]);
    }
    __syncthreads();

    int wave = tid >> 6, lane = tid & 63;
    int rb = blockIdx.x * 64 + wave * 16;
    int lr = lane & 15, lk = lane >> 4;

    f32x4 acc[8] = {};
    int arow = rb + lr; if (arow >= M) arow = M - 1;
    const float* afp = feat + (size_t)arow * K;

    for (int k0 = 0; k0 < K; k0 += 32) {
        float4 fa = *(const float4*)(afp + k0 + lk * 8);
        float4 fb = *(const float4*)(afp + k0 + lk * 8 + 4);
        f16x8 a;
        a[0] = (_Float16)fa.x; a[1] = (_Float16)fa.y;
        a[2] = (_Float16)fa.z; a[3] = (_Float16)fa.w;
        a[4] = (_Float16)fb.x; a[5] = (_Float16)fb.y;
        a[6] = (_Float16)fb.z; a[7] = (_Float16)fb.w;
#pragma unroll
        for (int t = 0; t < 8; ++t) {
            f16x8 bf = *(const f16x8*)(&BT[(t * 16 + lr) * LDB + k0 + lk * 8]);
            acc[t] = __builtin_amdgcn_mfma_f32_16x16x32_f16(a, bf, acc[t], 0, 0, 0);
        }
    }

    float bv[8];
#pragma unroll
    for (int t = 0; t < 8; ++t) bv[t] = b[t * 16 + lr];
#pragma unroll
    for (int reg = 0; reg < 4; ++reg) {
        int r = rb + lk * 4 + reg;
        if (r < M) {
            float s = ns[row0 + r];
            size_t base = ((size_t)(row0 + r)) << 7;
#pragma unroll
            for (int t = 0; t < 8; ++t)
                g0[base + t * 16 + lr] = __float2half((acc[t][reg] + bv[t]) * s);
        }
    }
}

// ---------------- hop: wave per node; deg-adaptive branch-free groups ----------
template<int FINAL>
__global__ __launch_bounds__(256) void hop_kernel(
    const __half* __restrict__ gc, __half* __restrict__ gn,
    const unsigned* __restrict__ ideg, const unsigned short* __restrict__ csr,
    const float* __restrict__ nsd,
    const __half* __restrict__ g0b, const float* __restrict__ rns,
    const float* __restrict__ ln0g, const float* __restrict__ ln0b)
{
    int node = blockIdx.x * 4 + (threadIdx.x >> 6);
    int lane = threadIdx.x & 63;
    int sub = lane >> 4;
    int ch8 = lane & 15;
    int dd = (int)ideg[node];
    int beg = node << 6;

    float a[8] = {0.f, 0.f, 0.f, 0.f, 0.f, 0.f, 0.f, 0.f};

    // group 1: slots 0..15 unconditional (csr pre-filled with dummy node NN)
    int i0 = beg + sub;
    int sidA0 = (int)csr[i0];
    int sidA1 = (int)csr[i0 + 4];
    int sidA2 = (int)csr[i0 + 8];
    int sidA3 = (int)csr[i0 + 12];
    int4 vA0 = *(const int4*)(gc + ((size_t)sidA0 << 7) + (ch8 << 3));
    int4 vA1 = *(const int4*)(gc + ((size_t)sidA1 << 7) + (ch8 << 3));
    int4 vA2 = *(const int4*)(gc + ((size_t)sidA2 << 7) + (ch8 << 3));
    int4 vA3 = *(const int4*)(gc + ((size_t)sidA3 << 7) + (ch8 << 3));

    bool more = dd > 16;   // wave-uniform (1 wave = 1 node)
    int4 vB0, vB1, vB2, vB3;
    if (more) {
        int i1 = beg + 16 + sub;
        int sidB0 = (int)csr[i1];
        int sidB1 = (int)csr[i1 + 4];
        int sidB2 = (int)csr[i1 + 8];
        int sidB3 = (int)csr[i1 + 12];
        vB0 = *(const int4*)(gc + ((size_t)sidB0 << 7) + (ch8 << 3));
        vB1 = *(const int4*)(gc + ((size_t)sidB1 << 7) + (ch8 << 3));
        vB2 = *(const int4*)(gc + ((size_t)sidB2 << 7) + (ch8 << 3));
        vB3 = *(const int4*)(gc + ((size_t)sidB3 << 7) + (ch8 << 3));
    }

    {
        float2 f;
        f = __half22float2(*(__half2*)&vA0.x); a[0] += f.x; a[1] += f.y;
        f = __half22float2(*(__half2*)&vA0.y); a[2] += f.x; a[3] += f.y;
        f = __half22float2(*(__half2*)&vA0.z); a[4] += f.x; a[5] += f.y;
        f = __half22float2(*(__half2*)&vA0.w); a[6] += f.x; a[7] += f.y;
        f = __half22float2(*(__half2*)&vA1.x); a[0] += f.x; a[1] += f.y;
        f = __half22float2(*(__half2*)&vA1.y); a[2] += f.x; a[3] += f.y;
        f = __half22float2(*(__half2*)&vA1.z); a[4] += f.x; a[5] += f.y;
        f = __half22float2(*(__half2*)&vA1.w); a[6] += f.x; a[7] += f.y;
        f = __half22float2(*(__half2*)&vA2.x); a[0] += f.x; a[1] += f.y;
        f = __half22float2(*(__half2*)&vA2.y); a[2] += f.x; a[3] += f.y;
        f = __half22float2(*(__half2*)&vA2.z); a[4] += f.x; a[5] += f.y;
        f = __half22float2(*(__half2*)&vA2.w); a[6] += f.x; a[7] += f.y;
        f = __half22float2(*(__half2*)&vA3.x); a[0] += f.x; a[1] += f.y;
        f = __half22float2(*(__half2*)&vA3.y); a[2] += f.x; a[3] += f.y;
        f = __half22float2(*(__half2*)&vA3.z); a[4] += f.x; a[5] += f.y;
        f = __half22float2(*(__half2*)&vA3.w); a[6] += f.x; a[7] += f.y;
    }
    if (more) {
        float2 f;
        f = __half22float2(*(__half2*)&vB0.x); a[0] += f.x; a[1] += f.y;
        f = __half22float2(*(__half2*)&vB0.y); a[2] += f.x; a[3] += f.y;
        f = __half22float2(*(__half2*)&vB0.z); a[4] += f.x; a[5] += f.y;
        f = __half22float2(*(__half2*)&vB0.w); a[6] += f.x; a[7] += f.y;
        f = __half22float2(*(__half2*)&vB1.x); a[0] += f.x; a[1] += f.y;
        f = __half22float2(*(__half2*)&vB1.y); a[2] += f.x; a[3] += f.y;
        f = __half22float2(*(__half2*)&vB1.z); a[4] += f.x; a[5] += f.y;
        f = __half22float2(*(__half2*)&vB1.w); a[6] += f.x; a[7] += f.y;
        f = __half22float2(*(__half2*)&vB2.x); a[0] += f.x; a[1] += f.y;
        f = __half22float2(*(__half2*)&vB2.y); a[2] += f.x; a[3] += f.y;
        f = __half22float2(*(__half2*)&vB2.z); a[4] += f.x; a[5] += f.y;
        f = __half22float2(*(__half2*)&vB2.w); a[6] += f.x; a[7] += f.y;
        f = __half22float2(*(__half2*)&vB3.x); a[0] += f.x; a[1] += f.y;
        f = __half22float2(*(__half2*)&vB3.y); a[2] += f.x; a[3] += f.y;
        f = __half22float2(*(__half2*)&vB3.z); a[4] += f.x; a[5] += f.y;
        f = __half22float2(*(__half2*)&vB3.w); a[6] += f.x; a[7] += f.y;
    }
    // rare tail: deg > 32 (Poisson(16) tail)
    if (dd > 32) {
        int len = dd > RCAP ? RCAP : ((dd + 15) & ~15);
        for (int base = beg + 32; base < beg + len; base += 16) {
            int i = base + sub;
            int s0 = (int)csr[i];
            int s1 = (int)csr[i + 4];
            int s2 = (int)csr[i + 8];
            int s3 = (int)csr[i + 12];
            int4 v0 = *(const int4*)(gc + ((size_t)s0 << 7) + (ch8 << 3));
            int4 v1 = *(const int4*)(gc + ((size_t)s1 << 7) + (ch8 << 3));
            int4 v2 = *(const int4*)(gc + ((size_t)s2 << 7) + (ch8 << 3));
            int4 v3 = *(const int4*)(gc + ((size_t)s3 << 7) + (ch8 << 3));
            float2 f;
            f = __half22float2(*(__half2*)&v0.x); a[0] += f.x; a[1] += f.y;
            f = __half22float2(*(__half2*)&v0.y); a[2] += f.x; a[3] += f.y;
            f = __half22float2(*(__half2*)&v0.z); a[4] += f.x; a[5] += f.y;
            f = __half22float2(*(__half2*)&v0.w); a[6] += f.x; a[7] += f.y;
            f = __half22float2(*(__half2*)&v1.x); a[0] += f.x; a[1] += f.y;
            f = __half22float2(*(__half2*)&v1.y); a[2] += f.x; a[3] += f.y;
            f = __half22float2(*(__half2*)&v1.z); a[4] += f.x; a[5] += f.y;
            f = __half22float2(*(__half2*)&v1.w); a[6] += f.x; a[7] += f.y;
            f = __half22float2(*(__half2*)&v2.x); a[0] += f.x; a[1] += f.y;
            f = __half22float2(*(__half2*)&v2.y); a[2] += f.x; a[3] += f.y;
            f = __half22float2(*(__half2*)&v2.z); a[4] += f.x; a[5] += f.y;
            f = __half22float2(*(__half2*)&v2.w); a[6] += f.x; a[7] += f.y;
            f = __half22float2(*(__half2*)&v3.x); a[0] += f.x; a[1] += f.y;
            f = __half22float2(*(__half2*)&v3.y); a[2] += f.x; a[3] += f.y;
            f = __half22float2(*(__half2*)&v3.z); a[4] += f.x; a[5] += f.y;
            f = __half22float2(*(__half2*)&v3.w); a[6] += f.x; a[7] += f.y;
        }
    }
#pragma unroll
    for (int j = 0; j < 8; ++j) {
        a[j] += __shfl_xor(a[j], 16);
        a[j] += __shfl_xor(a[j], 32);
    }

    if (!FINAL) {
        if (sub == 0) {
            float k = nsd[node];
            __half2 h0 = __float22half2_rn(make_float2(a[0] * k, a[1] * k));
            __half2 h1 = __float22half2_rn(make_float2(a[2] * k, a[3] * k));
            __half2 h2 = __float22half2_rn(make_float2(a[4] * k, a[5] * k));
            __half2 h3 = __float22half2_rn(make_float2(a[6] * k, a[7] * k));
            int4 w;
            w.x = *(int*)&h0; w.y = *(int*)&h1; w.z = *(int*)&h2; w.w = *(int*)&h3;
            *(int4*)(gn + ((size_t)node << 7) + (ch8 << 3)) = w;
        }
        return;
    }

    // ---- FINAL: x = rns*(sum_{k=0..7} g_k + a*nsd)/9, LN0, write xn fp16 ----
    float nsdv = nsd[node], rnsv = rns[node];
    const __half* r0 = g0b + (size_t)(2 * sub) * GSTRIDE + ((size_t)node << 7) + (ch8 << 3);
    int4 va = *(const int4*)r0;
    int4 vb = *(const int4*)(r0 + GSTRIDE);
    float gs[8];
    {
        float2 f0, f1;
        f0 = __half22float2(*(__half2*)&va.x); f1 = __half22float2(*(__half2*)&vb.x);
        gs[0] = f0.x + f1.x; gs[1] = f0.y + f1.y;
        f0 = __half22float2(*(__half2*)&va.y); f1 = __half22float2(*(__half2*)&vb.y);
        gs[2] = f0.x + f1.x; gs[3] = f0.y + f1.y;
        f0 = __half22float2(*(__half2*)&va.z); f1 = __half22float2(*(__half2*)&vb.z);
        gs[4] = f0.x + f1.x; gs[5] = f0.y + f1.y;
        f0 = __half22float2(*(__half2*)&va.w); f1 = __half22float2(*(__half2*)&vb.w);
        gs[6] = f0.x + f1.x; gs[7] = f0.y + f1.y;
    }
#pragma unroll
    for (int j = 0; j < 8; ++j) {
        gs[j] += __shfl_xor(gs[j], 16);
        gs[j] += __shfl_xor(gs[j], 32);
    }
    float x[8];
    float sc = rnsv * (1.0f / 9.0f);
#pragma unroll
    for (int j = 0; j < 8; ++j) x[j] = (gs[j] + a[j] * nsdv) * sc;

    float t = 0.f;
#pragma unroll
    for (int j = 0; j < 8; ++j) t += x[j];
#pragma unroll
    for (int m = 1; m < 16; m <<= 1) t += __shfl_xor(t, m);
    float mean = t * (1.0f / 128.0f);
    float q = 0.f;
#pragma unroll
    for (int j = 0; j < 8; ++j) { x[j] -= mean; q += x[j] * x[j]; }
#pragma unroll
    for (int m = 1; m < 16; m <<= 1) q += __shfl_xor(q, m);
    float rstd = rsqrtf(q * (1.0f / 128.0f) + 1e-5f);

    if (sub == 0) {
        int ch0 = ch8 << 3;
        float4 ga = *(const float4*)(ln0g + ch0);
        float4 gA = *(const float4*)(ln0g + ch0 + 4);
        float4 ba = *(const float4*)(ln0b + ch0);
        float4 bA = *(const float4*)(ln0b + ch0 + 4);
        __half2 h0 = __float22half2_rn(make_float2(x[0]*rstd*ga.x + ba.x, x[1]*rstd*ga.y + ba.y));
        __half2 h1 = __float22half2_rn(make_float2(x[2]*rstd*ga.z + ba.z, x[3]*rstd*ga.w + ba.w));
        __half2 h2 = __float22half2_rn(make_float2(x[4]*rstd*gA.x + bA.x, x[5]*rstd*gA.y + bA.y));
        __half2 h3 = __float22half2_rn(make_float2(x[6]*rstd*gA.z + bA.z, x[7]*rstd*gA.w + bA.w));
        int4 w;
        w.x = *(int*)&h0; w.y = *(int*)&h1; w.z = *(int*)&h2; w.w = *(int*)&h3;
        *(int4*)(gn + ((size_t)node << 7) + (ch8 << 3)) = w;
    }
}

// ---------------- mm2: y = ELU(xn@WpT+bp); LN1; logits = yn@WoT+bo; L2 norm ------
__global__ __launch_bounds__(256) void mm2_kernel(
    const __half* __restrict__ xn, const _Float16* __restrict__ WpT,
    const float* __restrict__ bp,
    const float* __restrict__ ln1g, const float* __restrict__ ln1b,
    const float* __restrict__ Wo, const float* __restrict__ bo,
    float* __restrict__ out)
{
    constexpr int LDB = 136;
    __shared__ _Float16 BT[128 * LDB];
    __shared__ _Float16 WoT[16 * LDB];
    __shared__ _Float16 YN[64 * LDB];
    int tid = threadIdx.x;
    for (int idx = tid * 8; idx < 128 * 128; idx += 256 * 8) {
        int n = idx >> 7, k = idx & 127;
        *(f16x8*)(&BT[n * LDB + k]) = *(const f16x8*)(&WpT[n * 128 + k]);
    }
    for (int idx = tid; idx < 2048; idx += 256) {
        int k = idx >> 4, c = idx & 15;
        WoT[c * LDB + k] = (_Float16)Wo[idx];
    }
    __syncthreads();

    int wave = tid >> 6, lane = tid & 63;
    int lr = lane & 15, lk = lane >> 4;
    int rb = blockIdx.x * 64 + wave * 16;

    f32x4 acc[8] = {};
    const __half* ap = xn + ((size_t)(rb + lr) << 7);
    for (int k0 = 0; k0 < 128; k0 += 32) {
        f16x8 a = *(const f16x8*)(ap + k0 + lk * 8);
#pragma unroll
        for (int t = 0; t < 8; ++t) {
            f16x8 bf = *(const f16x8*)(&BT[(t * 16 + lr) * LDB + k0 + lk * 8]);
            acc[t] = __builtin_amdgcn_mfma_f32_16x16x32_f16(a, bf, acc[t], 0, 0, 0);
        }
    }

    float bv[8], hg[8], hb[8];
#pragma unroll
    for (int t = 0; t < 8; ++t) {
        bv[t] = bp[t * 16 + lr];
        hg[t] = ln1g[t * 16 + lr];
        hb[t] = ln1b[t * 16 + lr];
    }
#pragma unroll
    for (int reg = 0; reg < 4; ++reg) {
        float y[8], S = 0.f;
#pragma unroll
        for (int t = 0; t < 8; ++t) {
            float v = acc[t][reg] + bv[t];
            v = v > 0.f ? v : (expf(v) - 1.f);
            y[t] = v; S += v;
        }
#pragma unroll
        for (int m = 1; m < 16; m <<= 1) S += __shfl_xor(S, m);
        float mean = S * (1.0f / 128.0f);
        float q = 0.f;
#pragma unroll
        for (int t = 0; t < 8; ++t) { y[t] -= mean; q += y[t] * y[t]; }
#pragma unroll
        for (int m = 1; m < 16; m <<= 1) q += __shfl_xor(q, m);
        float rstd = rsqrtf(q * (1.0f / 128.0f) + 1e-5f);
        int row_l = wave * 16 + lk * 4 + reg;
#pragma unroll
        for (int t = 0; t < 8; ++t)
            YN[row_l * LDB + t * 16 + lr] = (_Float16)(y[t] * rstd * hg[t] + hb[t]);
    }
    __syncthreads();

    f32x4 p = {};
    const _Float16* yrow = &YN[(wave * 16 + lr) * LDB];
    for (int k0 = 0; k0 < 128; k0 += 32) {
        f16x8 a = *(const f16x8*)(yrow + k0 + lk * 8);
        f16x8 bf = *(const f16x8*)(&WoT[lr * LDB + k0 + lk * 8]);
        p = __builtin_amdgcn_mfma_f32_16x16x32_f16(a, bf, p, 0, 0, 0);
    }
    float bol = bo[lr];
#pragma unroll
    for (int reg = 0; reg < 4; ++reg) {
        float logit = p[reg] + bol;
        float ss = logit * logit;
#pragma unroll
        for (int m = 1; m < 16; m <<= 1) ss += __shfl_xor(ss, m);
        float rinv = 1.0f / fmaxf(sqrtf(ss), 1e-12f);
        int row = rb + lk * 4 + reg;
        out[(size_t)row * 16 + lr] = logit * rinv;
    }
}

// ---------------- launch ----------------
extern "C" void kernel_launch(void* const* d_in, const int* in_sizes, int n_in,
                              void* d_out, int out_size, void* d_ws, size_t ws_size,
                              hipStream_t stream)
{
    const float* feat0 = (const float*)d_in[0];
    const float* feat1 = (const float*)d_in[1];
    const int*   src   = (const int*)d_in[2];
    const int*   dst   = (const int*)d_in[3];
    const float* W0    = (const float*)d_in[4];
    const float* b0    = (const float*)d_in[5];
    const float* W1    = (const float*)d_in[6];
    const float* b1    = (const float*)d_in[7];
    const float* ln0_g = (const float*)d_in[8];
    const float* ln0_b = (const float*)d_in[9];
    const float* ln1_g = (const float*)d_in[10];
    const float* ln1_b = (const float*)d_in[11];
    const float* Wp    = (const float*)d_in[12];
    const float* bp    = (const float*)d_in[13];
    const float* Wo    = (const float*)d_in[14];
    const float* bo    = (const float*)d_in[15];
    float* out = (float*)d_out;

    char* ws = (char*)d_ws;
    // layout (bytes); overlays noted
    __half*         gbuf  = (__half*)(ws + 0);            // 92,162,304
    unsigned*       ebuf  = (unsigned*)(ws + 0);          // 4,096,000 (dead before projmm)
    float*          ns    = (float*)(ws + 92162304);      // 160,000
    float*          nsd   = (float*)(ws + 92322304);      // 160,000
    unsigned*       odeg8 = (unsigned*)(ws + 92482304);   // 1,280,000
    unsigned*       bptr  = (unsigned*)(ws + 93762304);   // 8,000 (2000 uints)
    unsigned*       cnt   = (unsigned*)(ws + 93770304);   // 160,000
    unsigned short* csr   = (unsigned short*)(ws + 93930304); // 5,120,000 -> 99,050,304
    float*          rns   = (float*)(ws + 102402304);     // 160,000
    _Float16*       WT0   = (_Float16*)(ws + 102562304);  // 65,536
    _Float16*       WT1   = (_Float16*)(ws + 102627840);  // 32,768
    _Float16*       WpT   = (_Float16*)(ws + 102660608);  // 32,768 -> 102,693,376
    __half*         xbuf  = (__half*)(ws + 102693376);    // 10,240,000 -> 112,933,376
    // total ~112.9 MB

    setup_kernel<<<67, 256, 0, stream>>>(W0, WT0, W1, WT1, Wp, WpT, (unsigned*)gbuf);
    hipMemsetAsync(odeg8, 0, 1288000, stream);            // odeg8 + bptr (contiguous)

    partition_kernel<<<NE / 1024, 256, 0, stream>>>(src, dst, odeg8, bptr, ebuf);
    scatter_kernel<<<NRANGE, 256, 0, stream>>>(ebuf, bptr, odeg8, cnt, csr, ns, nsd, rns);

    projmm_kernel<256><<<(NT0 + 63) / 64, 256, 0, stream>>>(feat0, WT0, b0, ns, gbuf, 0, NT0);
    projmm_kernel<128><<<(NT0 + 63) / 64, 256, 0, stream>>>(feat1, WT1, b1, ns, gbuf, NT0, NT0);

    for (int h = 0; h < NHOPS - 1; ++h) {
        hop_kernel<0><<<NN / 4, 256, 0, stream>>>(gbuf + (size_t)h * GSTRIDE,
                                                  gbuf + (size_t)(h + 1) * GSTRIDE,
                                                  cnt, csr, nsd,
                                                  nullptr, nullptr, nullptr, nullptr);
    }
    // final hop: fused gsum + LN0 -> xbuf
    hop_kernel<1><<<NN / 4, 256, 0, stream>>>(gbuf + (size_t)(NHOPS - 1) * GSTRIDE,
                                              xbuf, cnt, csr, nsd,
                                              gbuf, rns, ln0_g, ln0_b);

    mm2_kernel<<<NN / 64, 256, 0, stream>>>(xbuf, WpT, bp, ln1_g, ln1_b, Wo, bo, out);
}

// Round 19
// 250.917 us; speedup vs baseline: 1.0348x; 1.0348x over previous
//
#include <hip/hip_runtime.h>
#include <hip/hip_fp16.h>
#include <math.h>

#define NN     40000
#define NT0    20000
#define NE     640000
#define NHOPS  8
#define RCAP   64
#define NRANGE 250                            // node ranges (160 nodes each)
#define SUBN   160                            // NRANGE * SUBN == NN exactly
#define SBCAP  512                            // per (xcd,range) bucket cap (avg 320)
#define GSTRIDE ((size_t)(NN + 1) * 128)      // elems per g buffer (row NN = dummy zero)

typedef _Float16 f16x8 __attribute__((ext_vector_type(8)));
typedef float    f32x4 __attribute__((ext_vector_type(4)));

// ---- setup: 3x weight transpose + g dummy-row zero + odeg8/bptr zero (1 kernel) --
__global__ __launch_bounds__(256) void setup_kernel(
    const float* __restrict__ W0, _Float16* __restrict__ WT0,
    const float* __restrict__ W1, _Float16* __restrict__ WT1,
    const float* __restrict__ Wp, _Float16* __restrict__ WpT,
    unsigned* __restrict__ gbase, unsigned* __restrict__ zbuf)
{
    // all 67 blocks: grid-stride zero of odeg8+bptr (322,000 uints)
    for (int i = blockIdx.x * 256 + threadIdx.x; i < 322000; i += 67 * 256)
        zbuf[i] = 0u;

    __shared__ float t[32][33];
    int b = blockIdx.x;
    const float* W; _Float16* WT; int K, lb;
    if (b < 32)      { W = W0; WT = WT0; K = 256; lb = b; }
    else if (b < 48) { W = W1; WT = WT1; K = 128; lb = b - 32; }
    else if (b < 64) { W = Wp; WT = WpT; K = 128; lb = b - 48; }
    else {
        int tt = (b - 64) * 256 + threadIdx.x;
        if (tt < 9 * 64) {
            int k = tt >> 6, j = tt & 63;
            gbase[(size_t)k * (GSTRIDE / 2) + ((size_t)NN << 6) + j] = 0u;
        }
        return;
    }
    int bk = (lb >> 2) * 32, bn = (lb & 3) * 32;
    int tx = threadIdx.x & 31, ty4 = (threadIdx.x >> 5) * 4;
#pragma unroll
    for (int i = 0; i < 4; ++i)
        t[ty4 + i][tx] = W[(size_t)(bk + ty4 + i) * 128 + bn + tx];
    __syncthreads();
#pragma unroll
    for (int i = 0; i < 4; ++i)
        WT[(size_t)(bn + ty4 + i) * K + bk + tx] = (_Float16)t[tx][ty4 + i];
}

// ---------------- phase A: partition edges into 8x250 XCD-private buckets --------
__global__ __launch_bounds__(256) void partition_kernel(
    const int* __restrict__ src, const int* __restrict__ dst,
    unsigned* __restrict__ odeg8, unsigned* __restrict__ bptr,
    unsigned* __restrict__ ebuf)
{
    __shared__ unsigned lhist[NRANGE];
    __shared__ unsigned gbase[NRANGE];
    int tid = threadIdx.x;
    for (int i = tid; i < NRANGE; i += 256) lhist[i] = 0u;
    __syncthreads();
    int xcd = blockIdx.x & 7;
    unsigned* myodeg = odeg8 + xcd * NN;
    int e0 = blockIdx.x * 1024 + tid;
    int s[4], d[4], bb[4];
    unsigned r[4];
#pragma unroll
    for (int j = 0; j < 4; ++j) {
        int e = e0 + j * 256;
        s[j] = src[e]; d[j] = dst[e];
    }
#pragma unroll
    for (int j = 0; j < 4; ++j) {
        atomicAdd(&myodeg[s[j]], 1u);
        bb[j] = d[j] / SUBN;
        r[j] = atomicAdd(&lhist[bb[j]], 1u);
    }
    __syncthreads();
    for (int i = tid; i < NRANGE; i += 256)
        gbase[i] = atomicAdd(&bptr[xcd * NRANGE + i], lhist[i]);
    __syncthreads();
#pragma unroll
    for (int j = 0; j < 4; ++j) {
        unsigned p = gbase[bb[j]] + r[j];
        if (p < SBCAP)
            ebuf[(xcd * NRANGE + bb[j]) * SBCAP + p] = ((unsigned)s[j] << 16) | (unsigned)d[j];
    }
}

// ---------------- phase B: block b owns 160 nodes; scatter + fused norms ----------
__global__ __launch_bounds__(256) void scatter_kernel(
    const unsigned* __restrict__ ebuf, const unsigned* __restrict__ bptr,
    const unsigned* __restrict__ odeg8,
    unsigned* __restrict__ cnt, unsigned short* __restrict__ csr,
    float* __restrict__ ns, float* __restrict__ nsd, float* __restrict__ rns)
{
    __shared__ unsigned short csrL[SUBN * RCAP];   // 20,480 B
    __shared__ unsigned cntL[SUBN];
    int b = blockIdx.x;
    int lo = b * SUBN;
    int tid = threadIdx.x;
    const unsigned pat = (40000u << 16) | 40000u;
    for (int i = tid; i < SUBN * RCAP / 2; i += 256) ((unsigned*)csrL)[i] = pat;
    for (int i = tid; i < SUBN; i += 256) cntL[i] = 0u;
    __syncthreads();
#pragma unroll
    for (int x = 0; x < 8; ++x) {
        unsigned count = bptr[x * NRANGE + b];
        if (count > SBCAP) count = SBCAP;
        const unsigned* eb = ebuf + (size_t)(x * NRANGE + b) * SBCAP;
        for (unsigned i = tid; i < count; i += 256) {
            unsigned pk = eb[i];
            int d = (int)(pk & 0xFFFFu) - lo;
            unsigned p = atomicAdd(&cntL[d], 1u);
            if (p < RCAP) csrL[(d << 6) + (int)p] = (unsigned short)(pk >> 16);
        }
    }
    __syncthreads();
    int4* dst4 = (int4*)(csr + ((size_t)lo << 6));
    const int4* src4 = (const int4*)csrL;
    for (int i = tid; i < SUBN * 8; i += 256) dst4[i] = src4[i];
    for (int i = tid; i < SUBN; i += 256) {
        int node = lo + i;
        cnt[node] = cntL[i];
        unsigned odu = 0;
#pragma unroll
        for (int k = 0; k < 8; ++k) odu += odeg8[k * NN + node];
        float od = fmaxf((float)odu, 1.0f);
        float s = rsqrtf(od);
        float d = rsqrtf(fmaxf((float)cntL[i], 1.0f));
        ns[node] = s; nsd[node] = s * d; rns[node] = sqrtf(od);
    }
}

// ---------------- MFMA projection body (shared LDS passed in) ----------
template<int K>
__device__ __forceinline__ void projmm_body(
    const float* __restrict__ feat, const _Float16* __restrict__ WT,
    const float* __restrict__ b, const float* __restrict__ ns,
    __half* __restrict__ g0, int row0, int M, int blk, _Float16* BT)
{
    constexpr int LDB = K + 8;
    int tid = threadIdx.x;
    for (int idx = tid * 8; idx < 128 * K; idx += 256 * 8) {
        int n = idx / K, k = idx % K;
        *(f16x8*)(&BT[n * LDB + k]) = *(const f16x8*)(&WT[n * K + k]);
    }
    __syncthreads();

    int wave = tid >> 6, lane = tid & 63;
    int rb = blk * 64 + wave * 16;
    int lr = lane & 15, lk = lane >> 4;

    f32x4 acc[8] = {};
    int arow = rb + lr; if (arow >= M) arow = M - 1;
    const float* afp = feat + (size_t)arow * K;

    for (int k0 = 0; k0 < K; k0 += 32) {
        float4 fa = *(const float4*)(afp + k0 + lk * 8);
        float4 fb = *(const float4*)(afp + k0 + lk * 8 + 4);
        f16x8 a;
        a[0] = (_Float16)fa.x; a[1] = (_Float16)fa.y;
        a[2] = (_Float16)fa.z; a[3] = (_Float16)fa.w;
        a[4] = (_Float16)fb.x; a[5] = (_Float16)fb.y;
        a[6] = (_Float16)fb.z; a[7] = (_Float16)fb.w;
#pragma unroll
        for (int t = 0; t < 8; ++t) {
            f16x8 bf = *(const f16x8*)(&BT[(t * 16 + lr) * LDB + k0 + lk * 8]);
            acc[t] = __builtin_amdgcn_mfma_f32_16x16x32_f16(a, bf, acc[t], 0, 0, 0);
        }
    }

    float bv[8];
#pragma unroll
    for (int t = 0; t < 8; ++t) bv[t] = b[t * 16 + lr];
#pragma unroll
    for (int reg = 0; reg < 4; ++reg) {
        int r = rb + lk * 4 + reg;
        if (r < M) {
            float s = ns[row0 + r];
            size_t base = ((size_t)(row0 + r)) << 7;
#pragma unroll
            for (int t = 0; t < 8; ++t)
                g0[base + t * 16 + lr] = __float2half((acc[t][reg] + bv[t]) * s);
        }
    }
}

// ---------------- merged projection: blocks 0..312 -> feat0; 313..625 -> feat1 ----
__global__ __launch_bounds__(256) void projmm_kernel(
    const float* __restrict__ feat0, const _Float16* __restrict__ WT0, const float* __restrict__ b0,
    const float* __restrict__ feat1, const _Float16* __restrict__ WT1, const float* __restrict__ b1,
    const float* __restrict__ ns, __half* __restrict__ g0)
{
    __shared__ _Float16 BT[128 * 264];   // sized for K=256 (LDB=264); reused for K=128
    if (blockIdx.x < 313)
        projmm_body<256>(feat0, WT0, b0, ns, g0, 0, NT0, blockIdx.x, BT);
    else
        projmm_body<128>(feat1, WT1, b1, ns, g0, NT0, NT0, blockIdx.x - 313, BT);
}

// ---------------- hop: wave per node; deg-adaptive branch-free groups ----------
template<int FINAL>
__global__ __launch_bounds__(256) void hop_kernel(
    const __half* __restrict__ gc, __half* __restrict__ gn,
    const unsigned* __restrict__ ideg, const unsigned short* __restrict__ csr,
    const float* __restrict__ nsd,
    const __half* __restrict__ g0b, const float* __restrict__ rns,
    const float* __restrict__ ln0g, const float* __restrict__ ln0b)
{
    int node = blockIdx.x * 4 + (threadIdx.x >> 6);
    int lane = threadIdx.x & 63;
    int sub = lane >> 4;
    int ch8 = lane & 15;
    int dd = (int)ideg[node];
    int beg = node << 6;

    float a[8] = {0.f, 0.f, 0.f, 0.f, 0.f, 0.f, 0.f, 0.f};

    // group 1: slots 0..15 unconditional (csr pre-filled with dummy node NN)
    int i0 = beg + sub;
    int sidA0 = (int)csr[i0];
    int sidA1 = (int)csr[i0 + 4];
    int sidA2 = (int)csr[i0 + 8];
    int sidA3 = (int)csr[i0 + 12];
    int4 vA0 = *(const int4*)(gc + ((size_t)sidA0 << 7) + (ch8 << 3));
    int4 vA1 = *(const int4*)(gc + ((size_t)sidA1 << 7) + (ch8 << 3));
    int4 vA2 = *(const int4*)(gc + ((size_t)sidA2 << 7) + (ch8 << 3));
    int4 vA3 = *(const int4*)(gc + ((size_t)sidA3 << 7) + (ch8 << 3));

    bool more = dd > 16;   // wave-uniform (1 wave = 1 node)
    int4 vB0, vB1, vB2, vB3;
    if (more) {
        int i1 = beg + 16 + sub;
        int sidB0 = (int)csr[i1];
        int sidB1 = (int)csr[i1 + 4];
        int sidB2 = (int)csr[i1 + 8];
        int sidB3 = (int)csr[i1 + 12];
        vB0 = *(const int4*)(gc + ((size_t)sidB0 << 7) + (ch8 << 3));
        vB1 = *(const int4*)(gc + ((size_t)sidB1 << 7) + (ch8 << 3));
        vB2 = *(const int4*)(gc + ((size_t)sidB2 << 7) + (ch8 << 3));
        vB3 = *(const int4*)(gc + ((size_t)sidB3 << 7) + (ch8 << 3));
    }

    {
        float2 f;
        f = __half22float2(*(__half2*)&vA0.x); a[0] += f.x; a[1] += f.y;
        f = __half22float2(*(__half2*)&vA0.y); a[2] += f.x; a[3] += f.y;
        f = __half22float2(*(__half2*)&vA0.z); a[4] += f.x; a[5] += f.y;
        f = __half22float2(*(__half2*)&vA0.w); a[6] += f.x; a[7] += f.y;
        f = __half22float2(*(__half2*)&vA1.x); a[0] += f.x; a[1] += f.y;
        f = __half22float2(*(__half2*)&vA1.y); a[2] += f.x; a[3] += f.y;
        f = __half22float2(*(__half2*)&vA1.z); a[4] += f.x; a[5] += f.y;
        f = __half22float2(*(__half2*)&vA1.w); a[6] += f.x; a[7] += f.y;
        f = __half22float2(*(__half2*)&vA2.x); a[0] += f.x; a[1] += f.y;
        f = __half22float2(*(__half2*)&vA2.y); a[2] += f.x; a[3] += f.y;
        f = __half22float2(*(__half2*)&vA2.z); a[4] += f.x; a[5] += f.y;
        f = __half22float2(*(__half2*)&vA2.w); a[6] += f.x; a[7] += f.y;
        f = __half22float2(*(__half2*)&vA3.x); a[0] += f.x; a[1] += f.y;
        f = __half22float2(*(__half2*)&vA3.y); a[2] += f.x; a[3] += f.y;
        f = __half22float2(*(__half2*)&vA3.z); a[4] += f.x; a[5] += f.y;
        f = __half22float2(*(__half2*)&vA3.w); a[6] += f.x; a[7] += f.y;
    }
    if (more) {
        float2 f;
        f = __half22float2(*(__half2*)&vB0.x); a[0] += f.x; a[1] += f.y;
        f = __half22float2(*(__half2*)&vB0.y); a[2] += f.x; a[3] += f.y;
        f = __half22float2(*(__half2*)&vB0.z); a[4] += f.x; a[5] += f.y;
        f = __half22float2(*(__half2*)&vB0.w); a[6] += f.x; a[7] += f.y;
        f = __half22float2(*(__half2*)&vB1.x); a[0] += f.x; a[1] += f.y;
        f = __half22float2(*(__half2*)&vB1.y); a[2] += f.x; a[3] += f.y;
        f = __half22float2(*(__half2*)&vB1.z); a[4] += f.x; a[5] += f.y;
        f = __half22float2(*(__half2*)&vB1.w); a[6] += f.x; a[7] += f.y;
        f = __half22float2(*(__half2*)&vB2.x); a[0] += f.x; a[1] += f.y;
        f = __half22float2(*(__half2*)&vB2.y); a[2] += f.x; a[3] += f.y;
        f = __half22float2(*(__half2*)&vB2.z); a[4] += f.x; a[5] += f.y;
        f = __half22float2(*(__half2*)&vB2.w); a[6] += f.x; a[7] += f.y;
        f = __half22float2(*(__half2*)&vB3.x); a[0] += f.x; a[1] += f.y;
        f = __half22float2(*(__half2*)&vB3.y); a[2] += f.x; a[3] += f.y;
        f = __half22float2(*(__half2*)&vB3.z); a[4] += f.x; a[5] += f.y;
        f = __half22float2(*(__half2*)&vB3.w); a[6] += f.x; a[7] += f.y;
    }
    // rare tail: deg > 32 (Poisson(16) tail)
    if (dd > 32) {
        int len = dd > RCAP ? RCAP : ((dd + 15) & ~15);
        for (int base = beg + 32; base < beg + len; base += 16) {
            int i = base + sub;
            int s0 = (int)csr[i];
            int s1 = (int)csr[i + 4];
            int s2 = (int)csr[i + 8];
            int s3 = (int)csr[i + 12];
            int4 v0 = *(const int4*)(gc + ((size_t)s0 << 7) + (ch8 << 3));
            int4 v1 = *(const int4*)(gc + ((size_t)s1 << 7) + (ch8 << 3));
            int4 v2 = *(const int4*)(gc + ((size_t)s2 << 7) + (ch8 << 3));
            int4 v3 = *(const int4*)(gc + ((size_t)s3 << 7) + (ch8 << 3));
            float2 f;
            f = __half22float2(*(__half2*)&v0.x); a[0] += f.x; a[1] += f.y;
            f = __half22float2(*(__half2*)&v0.y); a[2] += f.x; a[3] += f.y;
            f = __half22float2(*(__half2*)&v0.z); a[4] += f.x; a[5] += f.y;
            f = __half22float2(*(__half2*)&v0.w); a[6] += f.x; a[7] += f.y;
            f = __half22float2(*(__half2*)&v1.x); a[0] += f.x; a[1] += f.y;
            f = __half22float2(*(__half2*)&v1.y); a[2] += f.x; a[3] += f.y;
            f = __half22float2(*(__half2*)&v1.z); a[4] += f.x; a[5] += f.y;
            f = __half22float2(*(__half2*)&v1.w); a[6] += f.x; a[7] += f.y;
            f = __half22float2(*(__half2*)&v2.x); a[0] += f.x; a[1] += f.y;
            f = __half22float2(*(__half2*)&v2.y); a[2] += f.x; a[3] += f.y;
            f = __half22float2(*(__half2*)&v2.z); a[4] += f.x; a[5] += f.y;
            f = __half22float2(*(__half2*)&v2.w); a[6] += f.x; a[7] += f.y;
            f = __half22float2(*(__half2*)&v3.x); a[0] += f.x; a[1] += f.y;
            f = __half22float2(*(__half2*)&v3.y); a[2] += f.x; a[3] += f.y;
            f = __half22float2(*(__half2*)&v3.z); a[4] += f.x; a[5] += f.y;
            f = __half22float2(*(__half2*)&v3.w); a[6] += f.x; a[7] += f.y;
        }
    }
#pragma unroll
    for (int j = 0; j < 8; ++j) {
        a[j] += __shfl_xor(a[j], 16);
        a[j] += __shfl_xor(a[j], 32);
    }

    if (!FINAL) {
        if (sub == 0) {
            float k = nsd[node];
            __half2 h0 = __float22half2_rn(make_float2(a[0] * k, a[1] * k));
            __half2 h1 = __float22half2_rn(make_float2(a[2] * k, a[3] * k));
            __half2 h2 = __float22half2_rn(make_float2(a[4] * k, a[5] * k));
            __half2 h3 = __float22half2_rn(make_float2(a[6] * k, a[7] * k));
            int4 w;
            w.x = *(int*)&h0; w.y = *(int*)&h1; w.z = *(int*)&h2; w.w = *(int*)&h3;
            *(int4*)(gn + ((size_t)node << 7) + (ch8 << 3)) = w;
        }
        return;
    }

    // ---- FINAL: x = rns*(sum_{k=0..7} g_k + a*nsd)/9, LN0, write xn fp16 ----
    float nsdv = nsd[node], rnsv = rns[node];
    const __half* r0 = g0b + (size_t)(2 * sub) * GSTRIDE + ((size_t)node << 7) + (ch8 << 3);
    int4 va = *(const int4*)r0;
    int4 vb = *(const int4*)(r0 + GSTRIDE);
    float gs[8];
    {
        float2 f0, f1;
        f0 = __half22float2(*(__half2*)&va.x); f1 = __half22float2(*(__half2*)&vb.x);
        gs[0] = f0.x + f1.x; gs[1] = f0.y + f1.y;
        f0 = __half22float2(*(__half2*)&va.y); f1 = __half22float2(*(__half2*)&vb.y);
        gs[2] = f0.x + f1.x; gs[3] = f0.y + f1.y;
        f0 = __half22float2(*(__half2*)&va.z); f1 = __half22float2(*(__half2*)&vb.z);
        gs[4] = f0.x + f1.x; gs[5] = f0.y + f1.y;
        f0 = __half22float2(*(__half2*)&va.w); f1 = __half22float2(*(__half2*)&vb.w);
        gs[6] = f0.x + f1.x; gs[7] = f0.y + f1.y;
    }
#pragma unroll
    for (int j = 0; j < 8; ++j) {
        gs[j] += __shfl_xor(gs[j], 16);
        gs[j] += __shfl_xor(gs[j], 32);
    }
    float x[8];
    float sc = rnsv * (1.0f / 9.0f);
#pragma unroll
    for (int j = 0; j < 8; ++j) x[j] = (gs[j] + a[j] * nsdv) * sc;

    float t = 0.f;
#pragma unroll
    for (int j = 0; j < 8; ++j) t += x[j];
#pragma unroll
    for (int m = 1; m < 16; m <<= 1) t += __shfl_xor(t, m);
    float mean = t * (1.0f / 128.0f);
    float q = 0.f;
#pragma unroll
    for (int j = 0; j < 8; ++j) { x[j] -= mean; q += x[j] * x[j]; }
#pragma unroll
    for (int m = 1; m < 16; m <<= 1) q += __shfl_xor(q, m);
    float rstd = rsqrtf(q * (1.0f / 128.0f) + 1e-5f);

    if (sub == 0) {
        int ch0 = ch8 << 3;
        float4 ga = *(const float4*)(ln0g + ch0);
        float4 gA = *(const float4*)(ln0g + ch0 + 4);
        float4 ba = *(const float4*)(ln0b + ch0);
        float4 bA = *(const float4*)(ln0b + ch0 + 4);
        __half2 h0 = __float22half2_rn(make_float2(x[0]*rstd*ga.x + ba.x, x[1]*rstd*ga.y + ba.y));
        __half2 h1 = __float22half2_rn(make_float2(x[2]*rstd*ga.z + ba.z, x[3]*rstd*ga.w + ba.w));
        __half2 h2 = __float22half2_rn(make_float2(x[4]*rstd*gA.x + bA.x, x[5]*rstd*gA.y + bA.y));
        __half2 h3 = __float22half2_rn(make_float2(x[6]*rstd*gA.z + bA.z, x[7]*rstd*gA.w + bA.w));
        int4 w;
        w.x = *(int*)&h0; w.y = *(int*)&h1; w.z = *(int*)&h2; w.w = *(int*)&h3;
        *(int4*)(gn + ((size_t)node << 7) + (ch8 << 3)) = w;
    }
}

// ---------------- mm2: y = ELU(xn@WpT+bp); LN1; logits = yn@WoT+bo; L2 norm ------
__global__ __launch_bounds__(256) void mm2_kernel(
    const __half* __restrict__ xn, const _Float16* __restrict__ WpT,
    const float* __restrict__ bp,
    const float* __restrict__ ln1g, const float* __restrict__ ln1b,
    const float* __restrict__ Wo, const float* __restrict__ bo,
    float* __restrict__ out)
{
    constexpr int LDB = 136;
    __shared__ _Float16 BT[128 * LDB];
    __shared__ _Float16 WoT[16 * LDB];
    __shared__ _Float16 YN[64 * LDB];
    int tid = threadIdx.x;
    for (int idx = tid * 8; idx < 128 * 128; idx += 256 * 8) {
        int n = idx >> 7, k = idx & 127;
        *(f16x8*)(&BT[n * LDB + k]) = *(const f16x8*)(&WpT[n * 128 + k]);
    }
    for (int idx = tid; idx < 2048; idx += 256) {
        int k = idx >> 4, c = idx & 15;
        WoT[c * LDB + k] = (_Float16)Wo[idx];
    }
    __syncthreads();

    int wave = tid >> 6, lane = tid & 63;
    int lr = lane & 15, lk = lane >> 4;
    int rb = blockIdx.x * 64 + wave * 16;

    f32x4 acc[8] = {};
    const __half* ap = xn + ((size_t)(rb + lr) << 7);
    for (int k0 = 0; k0 < 128; k0 += 32) {
        f16x8 a = *(const f16x8*)(ap + k0 + lk * 8);
#pragma unroll
        for (int t = 0; t < 8; ++t) {
            f16x8 bf = *(const f16x8*)(&BT[(t * 16 + lr) * LDB + k0 + lk * 8]);
            acc[t] = __builtin_amdgcn_mfma_f32_16x16x32_f16(a, bf, acc[t], 0, 0, 0);
        }
    }

    float bv[8], hg[8], hb[8];
#pragma unroll
    for (int t = 0; t < 8; ++t) {
        bv[t] = bp[t * 16 + lr];
        hg[t] = ln1g[t * 16 + lr];
        hb[t] = ln1b[t * 16 + lr];
    }
#pragma unroll
    for (int reg = 0; reg < 4; ++reg) {
        float y[8], S = 0.f;
#pragma unroll
        for (int t = 0; t < 8; ++t) {
            float v = acc[t][reg] + bv[t];
            v = v > 0.f ? v : (expf(v) - 1.f);
            y[t] = v; S += v;
        }
#pragma unroll
        for (int m = 1; m < 16; m <<= 1) S += __shfl_xor(S, m);
        float mean = S * (1.0f / 128.0f);
        float q = 0.f;
#pragma unroll
        for (int t = 0; t < 8; ++t) { y[t] -= mean; q += y[t] * y[t]; }
#pragma unroll
        for (int m = 1; m < 16; m <<= 1) q += __shfl_xor(q, m);
        float rstd = rsqrtf(q * (1.0f / 128.0f) + 1e-5f);
        int row_l = wave * 16 + lk * 4 + reg;
#pragma unroll
        for (int t = 0; t < 8; ++t)
            YN[row_l * LDB + t * 16 + lr] = (_Float16)(y[t] * rstd * hg[t] + hb[t]);
    }
    __syncthreads();

    f32x4 p = {};
    const _Float16* yrow = &YN[(wave * 16 + lr) * LDB];
    for (int k0 = 0; k0 < 128; k0 += 32) {
        f16x8 a = *(const f16x8*)(yrow + k0 + lk * 8);
        f16x8 bf = *(const f16x8*)(&WoT[lr * LDB + k0 + lk * 8]);
        p = __builtin_amdgcn_mfma_f32_16x16x32_f16(a, bf, p, 0, 0, 0);
    }
    float bol = bo[lr];
#pragma unroll
    for (int reg = 0; reg < 4; ++reg) {
        float logit = p[reg] + bol;
        float ss = logit * logit;
#pragma unroll
        for (int m = 1; m < 16; m <<= 1) ss += __shfl_xor(ss, m);
        float rinv = 1.0f / fmaxf(sqrtf(ss), 1e-12f);
        int row = rb + lk * 4 + reg;
        out[(size_t)row * 16 + lr] = logit * rinv;
    }
}

// ---------------- launch ----------------
extern "C" void kernel_launch(void* const* d_in, const int* in_sizes, int n_in,
                              void* d_out, int out_size, void* d_ws, size_t ws_size,
                              hipStream_t stream)
{
    const float* feat0 = (const float*)d_in[0];
    const float* feat1 = (const float*)d_in[1];
    const int*   src   = (const int*)d_in[2];
    const int*   dst   = (const int*)d_in[3];
    const float* W0    = (const float*)d_in[4];
    const float* b0    = (const float*)d_in[5];
    const float* W1    = (const float*)d_in[6];
    const float* b1    = (const float*)d_in[7];
    const float* ln0_g = (const float*)d_in[8];
    const float* ln0_b = (const float*)d_in[9];
    const float* ln1_g = (const float*)d_in[10];
    const float* ln1_b = (const float*)d_in[11];
    const float* Wp    = (const float*)d_in[12];
    const float* bp    = (const float*)d_in[13];
    const float* Wo    = (const float*)d_in[14];
    const float* bo    = (const float*)d_in[15];
    float* out = (float*)d_out;

    char* ws = (char*)d_ws;
    // layout (bytes); overlays noted
    __half*         gbuf  = (__half*)(ws + 0);            // 92,162,304
    unsigned*       ebuf  = (unsigned*)(ws + 0);          // 4,096,000 (dead before projmm)
    float*          ns    = (float*)(ws + 92162304);      // 160,000
    float*          nsd   = (float*)(ws + 92322304);      // 160,000
    unsigned*       odeg8 = (unsigned*)(ws + 92482304);   // 1,280,000
    unsigned*       bptr  = (unsigned*)(ws + 93762304);   // 8,000 (2000 uints)
    unsigned*       cnt   = (unsigned*)(ws + 93770304);   // 160,000
    unsigned short* csr   = (unsigned short*)(ws + 93930304); // 5,120,000 -> 99,050,304
    float*          rns   = (float*)(ws + 102402304);     // 160,000
    _Float16*       WT0   = (_Float16*)(ws + 102562304);  // 65,536
    _Float16*       WT1   = (_Float16*)(ws + 102627840);  // 32,768
    _Float16*       WpT   = (_Float16*)(ws + 102660608);  // 32,768 -> 102,693,376
    __half*         xbuf  = (__half*)(ws + 102693376);    // 10,240,000 -> 112,933,376
    // total ~112.9 MB

    // setup: weight transposes + g dummy-row zero + odeg8/bptr zero (replaces memset)
    setup_kernel<<<67, 256, 0, stream>>>(W0, WT0, W1, WT1, Wp, WpT,
                                         (unsigned*)gbuf, odeg8);

    partition_kernel<<<NE / 1024, 256, 0, stream>>>(src, dst, odeg8, bptr, ebuf);
    scatter_kernel<<<NRANGE, 256, 0, stream>>>(ebuf, bptr, odeg8, cnt, csr, ns, nsd, rns);

    // merged projection (both node types in one dispatch)
    projmm_kernel<<<626, 256, 0, stream>>>(feat0, WT0, b0, feat1, WT1, b1, ns, gbuf);

    for (int h = 0; h < NHOPS - 1; ++h) {
        hop_kernel<0><<<NN / 4, 256, 0, stream>>>(gbuf + (size_t)h * GSTRIDE,
                                                  gbuf + (size_t)(h + 1) * GSTRIDE,
                                                  cnt, csr, nsd,
                                                  nullptr, nullptr, nullptr, nullptr);
    }
    // final hop: fused gsum + LN0 -> xbuf
    hop_kernel<1><<<NN / 4, 256, 0, stream>>>(gbuf + (size_t)(NHOPS - 1) * GSTRIDE,
                                              xbuf, cnt, csr, nsd,
                                              gbuf, rns, ln0_g, ln0_b);

    mm2_kernel<<<NN / 64, 256, 0, stream>>>(xbuf, WpT, bp, ln1_g, ln1_b, Wo, bo, out);
}